// Round 1
// baseline (734.040 us; speedup 1.0000x reference)
//
#include <hip/hip_runtime.h>

#define HW   784
#define CIN  4096
#define COUT 4
#define NIMG 32
#define CCHUNK 128
#define NCHUNK (CIN / CCHUNK)   // 32
#define F4_PER_IMG (CIN * (HW / 4))   // 802816
#define HW4 (HW / 4)                  // 196

// ws layout (floats):
//   [0, NIMG*COUT*HW)            : cams_raw (pre-relu sums, atomically accumulated)
//   [NIMG*COUT*HW, +NIMG*HW)     : s (per-pixel scale)

__global__ __launch_bounds__(256) void k1_cams(const float* __restrict__ x,
                                               const float* __restrict__ w,
                                               float* __restrict__ cams_raw) {
    const int n  = blockIdx.x;   // image
    const int cc = blockIdx.y;   // channel chunk
    const int t  = threadIdx.x;  // 0..255

    __shared__ float wlds[COUT][CCHUNK];
    for (int i = t; i < COUT * CCHUNK; i += 256) {
        int o = i / CCHUNK, c = i % CCHUNK;
        wlds[o][c] = w[o * CIN + cc * CCHUNK + c];
    }
    __syncthreads();

    const float* xp = x + ((size_t)n * CIN + (size_t)cc * CCHUNK) * HW;
    const bool has4 = (t < HW - 768);  // t < 16

    float acc0[COUT] = {0.f, 0.f, 0.f, 0.f};
    float acc1[COUT] = {0.f, 0.f, 0.f, 0.f};
    float acc2[COUT] = {0.f, 0.f, 0.f, 0.f};
    float acc3[COUT] = {0.f, 0.f, 0.f, 0.f};

    for (int c = 0; c < CCHUNK; ++c) {
        const float* row = xp + (size_t)c * HW;
        float x0 = row[t];
        float x1 = row[t + 256];
        float x2 = row[t + 512];
        float x3 = has4 ? row[t + 768] : 0.0f;
        #pragma unroll
        for (int o = 0; o < COUT; ++o) {
            float wv = wlds[o][c];
            acc0[o] += x0 * wv;
            acc1[o] += x1 * wv;
            acc2[o] += x2 * wv;
            acc3[o] += x3 * wv;
        }
    }

    float* cp = cams_raw + (size_t)n * COUT * HW;
    #pragma unroll
    for (int o = 0; o < COUT; ++o) {
        atomicAdd(&cp[o * HW + t],        acc0[o]);
        atomicAdd(&cp[o * HW + t + 256],  acc1[o]);
        atomicAdd(&cp[o * HW + t + 512],  acc2[o]);
        if (has4) atomicAdd(&cp[o * HW + t + 768], acc3[o]);
    }
}

__global__ __launch_bounds__(256) void k2_scale(const float* __restrict__ cams_raw,
                                                const float* __restrict__ gama_p,
                                                float* __restrict__ s) {
    const int n = blockIdx.x;
    const int t = threadIdx.x;
    const float gama = gama_p[0];
    const float* cp = cams_raw + (size_t)n * COUT * HW;
    const bool has4 = (t < HW - 768);  // t < 16

    float cam[COUT][4];
    #pragma unroll
    for (int o = 0; o < COUT; ++o) {
        cam[o][0] = fmaxf(cp[o * HW + t],       0.f);
        cam[o][1] = fmaxf(cp[o * HW + t + 256], 0.f);
        cam[o][2] = fmaxf(cp[o * HW + t + 512], 0.f);
        cam[o][3] = has4 ? fmaxf(cp[o * HW + t + 768], 0.f) : 0.f;
    }

    __shared__ float red[COUT][256];
    #pragma unroll
    for (int o = 0; o < COUT; ++o)
        red[o][t] = fmaxf(fmaxf(cam[o][0], cam[o][1]), fmaxf(cam[o][2], cam[o][3]));
    __syncthreads();
    for (int str = 128; str > 0; str >>= 1) {
        if (t < str) {
            #pragma unroll
            for (int o = 0; o < COUT; ++o)
                red[o][t] = fmaxf(red[o][t], red[o][t + str]);
        }
        __syncthreads();
    }
    float thr[COUT];
    #pragma unroll
    for (int o = 0; o < COUT; ++o) thr[o] = red[o][0] * gama;

    float s0 = 0.f, s1 = 0.f, s2 = 0.f, s3 = 0.f;
    #pragma unroll
    for (int o = 0; o < COUT; ++o) {
        s0 += (cam[o][0] > thr[o]) ? 0.f : cam[o][0];
        s1 += (cam[o][1] > thr[o]) ? 0.f : cam[o][1];
        s2 += (cam[o][2] > thr[o]) ? 0.f : cam[o][2];
        s3 += (cam[o][3] > thr[o]) ? 0.f : cam[o][3];
    }
    float* sp = s + (size_t)n * HW;
    sp[t]        = s0 * 0.25f;
    sp[t + 256]  = s1 * 0.25f;
    sp[t + 512]  = s2 * 0.25f;
    if (has4) sp[t + 768] = s3 * 0.25f;
}

__global__ __launch_bounds__(256) void k3_mul(const float4* __restrict__ x4,
                                              const float* __restrict__ s,
                                              float4* __restrict__ out4) {
    const int n = blockIdx.y;
    const int g = blockIdx.x * 256 + threadIdx.x;  // 0 .. F4_PER_IMG-1
    const int hw4 = g % HW4;
    const size_t idx = (size_t)n * F4_PER_IMG + g;
    float4 xv = x4[idx];
    const float4* s4 = (const float4*)(s + (size_t)n * HW);
    float4 sv = s4[hw4];
    float4 ov;
    ov.x = xv.x * sv.x;
    ov.y = xv.y * sv.y;
    ov.z = xv.z * sv.z;
    ov.w = xv.w * sv.w;
    out4[idx] = ov;
}

extern "C" void kernel_launch(void* const* d_in, const int* in_sizes, int n_in,
                              void* d_out, int out_size, void* d_ws, size_t ws_size,
                              hipStream_t stream) {
    const float* x    = (const float*)d_in[0];
    const float* w    = (const float*)d_in[1];
    const float* gama = (const float*)d_in[2];
    float* out = (float*)d_out;

    float* cams_raw = (float*)d_ws;
    float* s        = cams_raw + (size_t)NIMG * COUT * HW;

    // zero the atomic accumulation buffer (ws is poisoned each call)
    hipMemsetAsync(d_ws, 0, (size_t)NIMG * COUT * HW * sizeof(float), stream);

    k1_cams<<<dim3(NIMG, NCHUNK), 256, 0, stream>>>(x, w, cams_raw);
    k2_scale<<<NIMG, 256, 0, stream>>>(cams_raw, gama, s);
    k3_mul<<<dim3(F4_PER_IMG / 256, NIMG), 256, 0, stream>>>(
        (const float4*)x, s, (float4*)out);
}